// Round 3
// baseline (530.364 us; speedup 1.0000x reference)
//
#include <hip/hip_runtime.h>

// Problem constants (B=4, C=512, G=32, H=W=64)
#define B_   4
#define C_   512
#define G_   32
#define CPG  16          // channels per group
#define N_   4096        // H*W

typedef unsigned short u16;
typedef __attribute__((ext_vector_type(4))) float f32x4;
typedef __attribute__((ext_vector_type(8))) short s16x8;
typedef __attribute__((ext_vector_type(8))) u16   u16x8;
typedef __attribute__((ext_vector_type(4))) u16   u16x4;

__device__ __forceinline__ u16 f2bf(float f) {
    union { float f; unsigned u; } x; x.f = f;
    unsigned r = x.u + 0x7fffu + ((x.u >> 16) & 1u);   // RNE
    return (u16)(r >> 16);
}

// ---------------------------------------------------------------------------
// GroupNorm statistics: one block per (b, g). Writes per-channel scale/shift.
// ---------------------------------------------------------------------------
__global__ __launch_bounds__(256)
void gn_stats_kernel(const float* __restrict__ x,
                     const float* __restrict__ gamma,
                     const float* __restrict__ beta,
                     float* __restrict__ scale,   // [B*C]
                     float* __restrict__ shift)   // [B*C]
{
    int bg = blockIdx.x;            // 0..127
    int b = bg >> 5, g = bg & 31;
    const float* base = x + (size_t)(b * C_ + g * CPG) * N_;
    const int nelem = CPG * N_;     // 65536
    int t = threadIdx.x;

    float s = 0.f, ss = 0.f;
    for (int i = t * 4; i < nelem; i += 256 * 4) {
        float4 v = *reinterpret_cast<const float4*>(base + i);
        s  += v.x + v.y + v.z + v.w;
        ss += v.x * v.x + v.y * v.y + v.z * v.z + v.w * v.w;
    }
    __shared__ float rs[256], rss[256];
    rs[t] = s; rss[t] = ss;
    __syncthreads();
    for (int off = 128; off > 0; off >>= 1) {
        if (t < off) { rs[t] += rs[t + off]; rss[t] += rss[t + off]; }
        __syncthreads();
    }
    __shared__ float mean_s, rstd_s;
    if (t == 0) {
        float mean = rs[0] / (float)nelem;
        float var  = rss[0] / (float)nelem - mean * mean;
        mean_s = mean;
        rstd_s = rsqrtf(var + 1e-6f);
    }
    __syncthreads();
    if (t < CPG) {
        int c = g * CPG + t;
        float sc = gamma[c] * rstd_s;
        scale[b * C_ + c] = sc;
        shift[b * C_ + c] = beta[c] - mean_s * sc;
    }
}

// ---------------------------------------------------------------------------
// Convert the four 512x512 weight matrices to bf16 (same [co][ci] layout).
// ---------------------------------------------------------------------------
__global__ __launch_bounds__(256)
void wcvt_kernel(const float* __restrict__ wq, const float* __restrict__ wk,
                 const float* __restrict__ wv, const float* __restrict__ wo,
                 u16* __restrict__ wqb, u16* __restrict__ wkb,
                 u16* __restrict__ wvb, u16* __restrict__ wob)
{
    int idx = (blockIdx.x * 256 + threadIdx.x) * 4;
    {
        float4 a = *reinterpret_cast<const float4*>(wq + idx);
        u16x4 r = { f2bf(a.x), f2bf(a.y), f2bf(a.z), f2bf(a.w) };
        *reinterpret_cast<u16x4*>(wqb + idx) = r;
    }
    {
        float4 a = *reinterpret_cast<const float4*>(wk + idx);
        u16x4 r = { f2bf(a.x), f2bf(a.y), f2bf(a.z), f2bf(a.w) };
        *reinterpret_cast<u16x4*>(wkb + idx) = r;
    }
    {
        float4 a = *reinterpret_cast<const float4*>(wv + idx);
        u16x4 r = { f2bf(a.x), f2bf(a.y), f2bf(a.z), f2bf(a.w) };
        *reinterpret_cast<u16x4*>(wvb + idx) = r;
    }
    {
        float4 a = *reinterpret_cast<const float4*>(wo + idx);
        u16x4 r = { f2bf(a.x), f2bf(a.y), f2bf(a.z), f2bf(a.w) };
        *reinterpret_cast<u16x4*>(wob + idx) = r;
    }
}

// ---------------------------------------------------------------------------
// GN-apply + transpose + bf16 convert: x[b][c][n] f32 -> nx_t[b][n][c] bf16.
// ---------------------------------------------------------------------------
__global__ __launch_bounds__(256)
void nxt_kernel(const float* __restrict__ x, const float* __restrict__ scale,
                const float* __restrict__ shift, u16* __restrict__ nx_t)
{
    int b  = blockIdx.z;
    int n0 = blockIdx.x * 64, c0 = blockIdx.y * 64;
    const float* xb = x + ((size_t)b * C_ + c0) * N_ + n0;
    u16* ob = nx_t + ((size_t)b * N_ + n0) * C_ + c0;
    int t = threadIdx.x;
    int tx = t & 15, ty = t >> 4;

    __shared__ float tile[64][65];
    #pragma unroll
    for (int r = 0; r < 4; ++r) {
        int c = ty * 4 + r;
        float sc = scale[b * C_ + c0 + c];
        float sh = shift[b * C_ + c0 + c];
        float4 v = *reinterpret_cast<const float4*>(xb + (size_t)c * N_ + tx * 4);
        tile[c][tx * 4 + 0] = v.x * sc + sh;
        tile[c][tx * 4 + 1] = v.y * sc + sh;
        tile[c][tx * 4 + 2] = v.z * sc + sh;
        tile[c][tx * 4 + 3] = v.w * sc + sh;
    }
    __syncthreads();
    int nn = t >> 2, cc0 = (t & 3) * 16;
    u16x8 o0, o1;
    #pragma unroll
    for (int j = 0; j < 8; ++j) o0[j] = f2bf(tile[cc0 + j][nn]);
    #pragma unroll
    for (int j = 0; j < 8; ++j) o1[j] = f2bf(tile[cc0 + 8 + j][nn]);
    *reinterpret_cast<u16x8*>(ob + (size_t)nn * C_ + cc0)     = o0;
    *reinterpret_cast<u16x8*>(ob + (size_t)nn * C_ + cc0 + 8) = o1;
}

// ---------------------------------------------------------------------------
// TN bf16 MFMA GEMM: D[i][j] = sum_k A[i][k] * B[j][k]
// BM x BN tile, BK=32, 4 waves (2x2), 16x16x32 MFMA.
// 2-phase double-buffered pipeline: global_load_lds for tile t+1 issued
// before the ds_read+MFMA of tile t; one counted vmcnt(0) + raw s_barrier
// per K-step (loads stay in flight UNDER the MFMA phase, not drained first).
// EPI: 0 = bf16 out + bias[j]; 1 = bf16 out + bias[i]; 2 = f32 out * scale;
//      3 = f32 out + bias[i] + resid[i][j]; 4 = bf16 out plain.
// ---------------------------------------------------------------------------
template<int BM, int BN, int EPI>
__device__ __forceinline__
void gemm_dev(const u16* __restrict__ A, const u16* __restrict__ B,
              void* __restrict__ Dp, const float* __restrict__ bias,
              const float* __restrict__ resid,
              int Nn, int K, int lda, int ldb, float scl)
{
    constexpr int WM = BM / 2, WN = BN / 2;   // wave tile
    constexpr int MI = WM / 16, NI = WN / 16; // fragments per wave

    __shared__ u16 As[2][BM * 32];
    __shared__ u16 Bs[2][BN * 32];

    const int i0 = blockIdx.y * BM;
    const int j0 = blockIdx.x * BN;
    const int t  = threadIdx.x;
    const int l  = t & 63;
    const int w  = t >> 6;          // wave 0..3
    const int wr = w >> 1;          // i-half
    const int wc = w & 1;           // j-half

    const int srow  = l >> 2;       // staging row within 16-row segment
    const int skoff = (l & 3) * 8;  // staging k element offset

    const int fr = l & 15;          // fragment row
    const int fk = (l >> 4) * 8;    // fragment k offset

    f32x4 acc[MI][NI];
    #pragma unroll
    for (int a = 0; a < MI; ++a)
        #pragma unroll
        for (int b2 = 0; b2 < NI; ++b2) acc[a][b2] = 0.f;

    auto stage = [&](int k0, int d) {
        #pragma unroll
        for (int r = 0; r < BM / 64; ++r) {
            int s = r * 4 + w;      // 16-row segment
            const u16* ga = A + (size_t)(i0 + s * 16 + srow) * lda + (k0 + skoff);
            __builtin_amdgcn_global_load_lds(
                (const __attribute__((address_space(1))) void*)ga,
                (__attribute__((address_space(3))) void*)&As[d][s * 512], 16, 0, 0);
        }
        #pragma unroll
        for (int r = 0; r < BN / 64; ++r) {
            int s = r * 4 + w;
            const u16* gb = B + (size_t)(j0 + s * 16 + srow) * ldb + (k0 + skoff);
            __builtin_amdgcn_global_load_lds(
                (const __attribute__((address_space(1))) void*)gb,
                (__attribute__((address_space(3))) void*)&Bs[d][s * 512], 16, 0, 0);
        }
    };

    // prologue: stage tile 0, drain, barrier
    stage(0, 0);
    asm volatile("s_waitcnt vmcnt(0)" ::: "memory");
    __builtin_amdgcn_s_barrier();
    asm volatile("" ::: "memory");

    const int NT = K / 32;
    int cur = 0;
    for (int tt = 0; tt < NT; ++tt) {
        if (tt + 1 < NT) stage((tt + 1) * 32, cur ^ 1);   // prefetch under MFMA

        s16x8 af[MI], bfr[NI];
        #pragma unroll
        for (int mi = 0; mi < MI; ++mi)
            af[mi] = *reinterpret_cast<const s16x8*>(
                &As[cur][(wr * WM + mi * 16 + fr) * 32 + fk]);
        #pragma unroll
        for (int ni = 0; ni < NI; ++ni)
            bfr[ni] = *reinterpret_cast<const s16x8*>(
                &Bs[cur][(wc * WN + ni * 16 + fr) * 32 + fk]);
        #pragma unroll
        for (int mi = 0; mi < MI; ++mi)
            #pragma unroll
            for (int ni = 0; ni < NI; ++ni)
                acc[mi][ni] = __builtin_amdgcn_mfma_f32_16x16x32_bf16(
                    af[mi], bfr[ni], acc[mi][ni], 0, 0, 0);

        asm volatile("s_waitcnt vmcnt(0)" ::: "memory");
        __builtin_amdgcn_s_barrier();
        asm volatile("" ::: "memory");
        cur ^= 1;
    }

    const int orow = (l >> 4) * 4;
    const int ocol = l & 15;
    #pragma unroll
    for (int mi = 0; mi < MI; ++mi) {
        #pragma unroll
        for (int ni = 0; ni < NI; ++ni) {
            int ib = i0 + wr * WM + mi * 16 + orow;
            int jb = j0 + wc * WN + ni * 16 + ocol;
            if constexpr (EPI == 0 || EPI == 1 || EPI == 4) {
                u16* D = (u16*)Dp;
                float bj = 0.f;
                if constexpr (EPI == 0) bj = bias[jb];
                #pragma unroll
                for (int e = 0; e < 4; ++e) {
                    float vv = acc[mi][ni][e];
                    if constexpr (EPI == 0) vv += bj;
                    if constexpr (EPI == 1) vv += bias[ib + e];
                    D[(size_t)(ib + e) * Nn + jb] = f2bf(vv);
                }
            } else if constexpr (EPI == 2) {
                float* D = (float*)Dp;
                #pragma unroll
                for (int e = 0; e < 4; ++e)
                    D[(size_t)(ib + e) * Nn + jb] = acc[mi][ni][e] * scl;
            } else {   // EPI == 3
                float* D = (float*)Dp;
                #pragma unroll
                for (int e = 0; e < 4; ++e)
                    D[(size_t)(ib + e) * Nn + jb] =
                        acc[mi][ni][e] + bias[ib + e] + resid[(size_t)(ib + e) * Nn + jb];
            }
        }
    }
}

// q_t/k_t: D[n][co] = sum_ci nx_t[n][ci] * W[co][ci] + b[co].  grid (4,32,8)
__global__ __launch_bounds__(256)
void qk_gemm(const u16* __restrict__ nx_t, const u16* __restrict__ wqb,
             const u16* __restrict__ wkb, const float* __restrict__ bq,
             const float* __restrict__ bk, u16* __restrict__ q_t,
             u16* __restrict__ k_t)
{
    int z = blockIdx.z, b = z & 3, isk = z >> 2;
    gemm_dev<128, 128, 0>(nx_t + (size_t)b * N_ * C_, isk ? wkb : wqb,
                          (isk ? k_t : q_t) + (size_t)b * N_ * C_,
                          isk ? bk : bq, nullptr, C_, C_, C_, C_, 1.f);
}

// v: D[co][n] = sum_ci Wv[co][ci] * nx_t[n][ci] + bv[co].  grid (64,4,4)
__global__ __launch_bounds__(256)
void v_gemm(const u16* __restrict__ wvb, const u16* __restrict__ nx_t,
            const float* __restrict__ bv, u16* __restrict__ vbuf)
{
    int b = blockIdx.z;
    gemm_dev<128, 64, 1>(wvb, nx_t + (size_t)b * N_ * C_, vbuf + (size_t)b * C_ * N_,
                         bv, nullptr, N_, C_, C_, C_, 1.f);
}

// scores: S[i][j] = (sum_c q_t[i][c]*k_t[j][c]) / sqrt(C).  grid (32,32,2)
__global__ __launch_bounds__(256)
void scores_gemm(const u16* __restrict__ q_t, const u16* __restrict__ k_t,
                 float* __restrict__ S0, float* __restrict__ S1, int pair)
{
    int z = blockIdx.z, b = pair * 2 + z;
    gemm_dev<128, 128, 2>(q_t + (size_t)b * N_ * C_, k_t + (size_t)b * N_ * C_,
                          z ? S1 : S0, nullptr, nullptr, N_, C_, C_, C_,
                          0.044194173824159216f);
}

// Row softmax over j; writes P bf16 into the FIRST HALF of each fp32 S row.
// grid (4096, 2)
__global__ __launch_bounds__(256)
void softmax_kernel(float* __restrict__ S0, float* __restrict__ S1)
{
    float* row = (blockIdx.y ? S1 : S0) + (size_t)blockIdx.x * N_;
    int t = threadIdx.x;
    __shared__ float red[256];

    float4 v[4];
    float mx = -1e30f;
    #pragma unroll
    for (int e = 0; e < 4; ++e) {
        v[e] = *reinterpret_cast<const float4*>(row + e * 1024 + t * 4);
        mx = fmaxf(mx, fmaxf(fmaxf(v[e].x, v[e].y), fmaxf(v[e].z, v[e].w)));
    }
    red[t] = mx; __syncthreads();
    for (int off = 128; off > 0; off >>= 1) {
        if (t < off) red[t] = fmaxf(red[t], red[t + off]);
        __syncthreads();
    }
    mx = red[0];
    __syncthreads();

    float sum = 0.f;
    #pragma unroll
    for (int e = 0; e < 4; ++e) {
        v[e].x = __expf(v[e].x - mx); v[e].y = __expf(v[e].y - mx);
        v[e].z = __expf(v[e].z - mx); v[e].w = __expf(v[e].w - mx);
        sum += v[e].x + v[e].y + v[e].z + v[e].w;
    }
    red[t] = sum; __syncthreads();
    for (int off = 128; off > 0; off >>= 1) {
        if (t < off) red[t] += red[t + off];
        __syncthreads();
    }
    float inv = 1.f / red[0];

    u16* P = (u16*)row;     // bf16 row, stride 2*N_ u16 across rows
    #pragma unroll
    for (int e = 0; e < 4; ++e) {
        int j = e * 1024 + t * 4;
        u16x4 o = { f2bf(v[e].x * inv), f2bf(v[e].y * inv),
                    f2bf(v[e].z * inv), f2bf(v[e].w * inv) };
        *reinterpret_cast<u16x4*>(P + j) = o;
    }
}

// PV: attn_t[i][c] = sum_j P[i][j] * v[c][j].  P lda = 2*N_ (in-place rows).
// grid (8, 32, 2) = 512 blocks
__global__ __launch_bounds__(256)
void pv_gemm(const float* __restrict__ S0, const float* __restrict__ S1,
             const u16* __restrict__ vbuf, u16* __restrict__ attn_t, int pair)
{
    int z = blockIdx.z, b = pair * 2 + z;
    const u16* P = (const u16*)(z ? S1 : S0);
    gemm_dev<128, 64, 4>(P, vbuf + (size_t)b * C_ * N_, attn_t + (size_t)b * N_ * C_,
                         nullptr, nullptr, C_, N_, 2 * N_, N_, 1.f);
}

// final: out[co][n] = x + bo[co] + sum_ci wo[co][ci]*attn_t[n][ci]. grid (64,4,4)
__global__ __launch_bounds__(256)
void final_gemm(const u16* __restrict__ wob, const u16* __restrict__ attn_t,
                const float* __restrict__ bo, const float* __restrict__ x,
                float* __restrict__ outp)
{
    int b = blockIdx.z;
    gemm_dev<128, 64, 3>(wob, attn_t + (size_t)b * N_ * C_, outp + (size_t)b * C_ * N_,
                         bo, x + (size_t)b * C_ * N_, N_, C_, C_, C_, 1.f);
}

// ---------------------------------------------------------------------------
extern "C" void kernel_launch(void* const* d_in, const int* in_sizes, int n_in,
                              void* d_out, int out_size, void* d_ws, size_t ws_size,
                              hipStream_t stream)
{
    const float* x     = (const float*)d_in[0];
    const float* gamma = (const float*)d_in[1];
    const float* beta  = (const float*)d_in[2];
    const float* wq    = (const float*)d_in[3];
    const float* bq    = (const float*)d_in[4];
    const float* wk    = (const float*)d_in[5];
    const float* bk    = (const float*)d_in[6];
    const float* wv    = (const float*)d_in[7];
    const float* bv    = (const float*)d_in[8];
    const float* wo    = (const float*)d_in[9];
    const float* bo    = (const float*)d_in[10];
    float* out = (float*)d_out;

    // Workspace carve (total ~194 MB):
    char* p = (char*)d_ws;
    auto take = [&](size_t bytes) { char* r = p; p += (bytes + 255) & ~(size_t)255; return r; };
    float* scale = (float*)take(B_ * C_ * 4);
    float* shift = (float*)take(B_ * C_ * 4);
    u16* wqb = (u16*)take((size_t)C_ * C_ * 2);
    u16* wkb = (u16*)take((size_t)C_ * C_ * 2);
    u16* wvb = (u16*)take((size_t)C_ * C_ * 2);
    u16* wob = (u16*)take((size_t)C_ * C_ * 2);
    u16* nx_t  = (u16*)take((size_t)B_ * N_ * C_ * 2);   // reused as attn_t
    u16* q_t   = (u16*)take((size_t)B_ * N_ * C_ * 2);
    u16* k_t   = (u16*)take((size_t)B_ * N_ * C_ * 2);
    u16* vbuf  = (u16*)take((size_t)B_ * C_ * N_ * 2);
    float* S0  = (float*)take((size_t)N_ * N_ * 4);
    float* S1  = (float*)take((size_t)N_ * N_ * 4);
    u16* attn_t = nx_t;    // nx_t is dead after qkv projections

    gn_stats_kernel<<<128, 256, 0, stream>>>(x, gamma, beta, scale, shift);
    wcvt_kernel<<<256, 256, 0, stream>>>(wq, wk, wv, wo, wqb, wkb, wvb, wob);
    nxt_kernel<<<dim3(N_ / 64, C_ / 64, B_), 256, 0, stream>>>(x, scale, shift, nx_t);

    qk_gemm<<<dim3(C_ / 128, N_ / 128, 8), 256, 0, stream>>>(nx_t, wqb, wkb, bq, bk, q_t, k_t);
    v_gemm<<<dim3(N_ / 64, C_ / 128, B_), 256, 0, stream>>>(wvb, nx_t, bv, vbuf);

    for (int pair = 0; pair < 2; ++pair) {
        scores_gemm<<<dim3(N_ / 128, N_ / 128, 2), 256, 0, stream>>>(q_t, k_t, S0, S1, pair);
        softmax_kernel<<<dim3(N_, 2), 256, 0, stream>>>(S0, S1);
        pv_gemm<<<dim3(C_ / 64, N_ / 128, 2), 256, 0, stream>>>(S0, S1, vbuf, attn_t, pair);
    }

    final_gemm<<<dim3(N_ / 64, C_ / 128, B_), 256, 0, stream>>>(wob, attn_t, bo, x, out);
}

// Round 4
// 414.312 us; speedup vs baseline: 1.2801x; 1.2801x over previous
//
#include <hip/hip_runtime.h>

// Problem constants (B=4, C=512, G=32, H=W=64)
#define B_   4
#define C_   512
#define G_   32
#define CPG  16          // channels per group
#define N_   4096        // H*W

typedef unsigned short u16;
typedef __attribute__((ext_vector_type(4))) float f32x4;
typedef __attribute__((ext_vector_type(8))) short s16x8;
typedef __attribute__((ext_vector_type(8))) u16   u16x8;
typedef __attribute__((ext_vector_type(4))) u16   u16x4;

__device__ __forceinline__ u16 f2bf(float f) {
    union { float f; unsigned u; } x; x.f = f;
    unsigned r = x.u + 0x7fffu + ((x.u >> 16) & 1u);   // RNE
    return (u16)(r >> 16);
}

// ---------------------------------------------------------------------------
// GroupNorm statistics: one block per (b, g). Writes per-channel scale/shift.
// ---------------------------------------------------------------------------
__global__ __launch_bounds__(256)
void gn_stats_kernel(const float* __restrict__ x,
                     const float* __restrict__ gamma,
                     const float* __restrict__ beta,
                     float* __restrict__ scale,   // [B*C]
                     float* __restrict__ shift)   // [B*C]
{
    int bg = blockIdx.x;            // 0..127
    int b = bg >> 5, g = bg & 31;
    const float* base = x + (size_t)(b * C_ + g * CPG) * N_;
    const int nelem = CPG * N_;     // 65536
    int t = threadIdx.x;

    float s = 0.f, ss = 0.f;
    for (int i = t * 4; i < nelem; i += 256 * 4) {
        float4 v = *reinterpret_cast<const float4*>(base + i);
        s  += v.x + v.y + v.z + v.w;
        ss += v.x * v.x + v.y * v.y + v.z * v.z + v.w * v.w;
    }
    __shared__ float rs[256], rss[256];
    rs[t] = s; rss[t] = ss;
    __syncthreads();
    for (int off = 128; off > 0; off >>= 1) {
        if (t < off) { rs[t] += rs[t + off]; rss[t] += rss[t + off]; }
        __syncthreads();
    }
    __shared__ float mean_s, rstd_s;
    if (t == 0) {
        float mean = rs[0] / (float)nelem;
        float var  = rss[0] / (float)nelem - mean * mean;
        mean_s = mean;
        rstd_s = rsqrtf(var + 1e-6f);
    }
    __syncthreads();
    if (t < CPG) {
        int c = g * CPG + t;
        float sc = gamma[c] * rstd_s;
        scale[b * C_ + c] = sc;
        shift[b * C_ + c] = beta[c] - mean_s * sc;
    }
}

// ---------------------------------------------------------------------------
// Convert the four 512x512 weight matrices to bf16 (same [co][ci] layout).
// ---------------------------------------------------------------------------
__global__ __launch_bounds__(256)
void wcvt_kernel(const float* __restrict__ wq, const float* __restrict__ wk,
                 const float* __restrict__ wv, const float* __restrict__ wo,
                 u16* __restrict__ wqb, u16* __restrict__ wkb,
                 u16* __restrict__ wvb, u16* __restrict__ wob)
{
    int idx = (blockIdx.x * 256 + threadIdx.x) * 4;
    {
        float4 a = *reinterpret_cast<const float4*>(wq + idx);
        u16x4 r = { f2bf(a.x), f2bf(a.y), f2bf(a.z), f2bf(a.w) };
        *reinterpret_cast<u16x4*>(wqb + idx) = r;
    }
    {
        float4 a = *reinterpret_cast<const float4*>(wk + idx);
        u16x4 r = { f2bf(a.x), f2bf(a.y), f2bf(a.z), f2bf(a.w) };
        *reinterpret_cast<u16x4*>(wkb + idx) = r;
    }
    {
        float4 a = *reinterpret_cast<const float4*>(wv + idx);
        u16x4 r = { f2bf(a.x), f2bf(a.y), f2bf(a.z), f2bf(a.w) };
        *reinterpret_cast<u16x4*>(wvb + idx) = r;
    }
    {
        float4 a = *reinterpret_cast<const float4*>(wo + idx);
        u16x4 r = { f2bf(a.x), f2bf(a.y), f2bf(a.z), f2bf(a.w) };
        *reinterpret_cast<u16x4*>(wob + idx) = r;
    }
}

// ---------------------------------------------------------------------------
// GN-apply + transpose + bf16 convert: x[b][c][n] f32 -> nx_t[b][n][c] bf16.
// ---------------------------------------------------------------------------
__global__ __launch_bounds__(256)
void nxt_kernel(const float* __restrict__ x, const float* __restrict__ scale,
                const float* __restrict__ shift, u16* __restrict__ nx_t)
{
    int b  = blockIdx.z;
    int n0 = blockIdx.x * 64, c0 = blockIdx.y * 64;
    const float* xb = x + ((size_t)b * C_ + c0) * N_ + n0;
    u16* ob = nx_t + ((size_t)b * N_ + n0) * C_ + c0;
    int t = threadIdx.x;
    int tx = t & 15, ty = t >> 4;

    __shared__ float tile[64][65];
    #pragma unroll
    for (int r = 0; r < 4; ++r) {
        int c = ty * 4 + r;
        float sc = scale[b * C_ + c0 + c];
        float sh = shift[b * C_ + c0 + c];
        float4 v = *reinterpret_cast<const float4*>(xb + (size_t)c * N_ + tx * 4);
        tile[c][tx * 4 + 0] = v.x * sc + sh;
        tile[c][tx * 4 + 1] = v.y * sc + sh;
        tile[c][tx * 4 + 2] = v.z * sc + sh;
        tile[c][tx * 4 + 3] = v.w * sc + sh;
    }
    __syncthreads();
    int nn = t >> 2, cc0 = (t & 3) * 16;
    u16x8 o0, o1;
    #pragma unroll
    for (int j = 0; j < 8; ++j) o0[j] = f2bf(tile[cc0 + j][nn]);
    #pragma unroll
    for (int j = 0; j < 8; ++j) o1[j] = f2bf(tile[cc0 + 8 + j][nn]);
    *reinterpret_cast<u16x8*>(ob + (size_t)nn * C_ + cc0)     = o0;
    *reinterpret_cast<u16x8*>(ob + (size_t)nn * C_ + cc0 + 8) = o1;
}

// ---------------------------------------------------------------------------
// TN bf16 MFMA GEMM: D[i][j] = sum_k A[i][k] * B[j][k]
// BM x BN tile, BK=32, 4 waves (2x2), 16x16x32 MFMA, global_load_lds staging.
// Round-2 proven structure (single LDS buffer, __syncthreads pipeline).
// i0/j0 passed by caller (allows swizzled block->tile mapping).
// EPI: 0 = bf16 out + bias[j]; 1 = bf16 out + bias[i]; 2 = f32 out * scale;
//      3 = f32 out + bias[i] + resid[i][j]; 4 = bf16 out plain.
// ---------------------------------------------------------------------------
template<int BM, int BN, int EPI>
__device__ __forceinline__
void gemm_dev(int i0, int j0,
              const u16* __restrict__ A, const u16* __restrict__ B,
              void* __restrict__ Dp, const float* __restrict__ bias,
              const float* __restrict__ resid,
              int Nn, int K, int lda, int ldb, float scl)
{
    constexpr int WM = BM / 2, WN = BN / 2;   // wave tile
    constexpr int MI = WM / 16, NI = WN / 16; // fragments per wave

    __shared__ u16 As[BM * 32];
    __shared__ u16 Bs[BN * 32];

    const int t  = threadIdx.x;
    const int l  = t & 63;
    const int w  = t >> 6;          // wave 0..3
    const int wr = w >> 1;          // i-half
    const int wc = w & 1;           // j-half

    const int srow  = l >> 2;       // staging row within 16-row segment
    const int skoff = (l & 3) * 8;  // staging k element offset

    const int fr = l & 15;          // fragment row
    const int fk = (l >> 4) * 8;    // fragment k offset

    f32x4 acc[MI][NI];
    #pragma unroll
    for (int a = 0; a < MI; ++a)
        #pragma unroll
        for (int b2 = 0; b2 < NI; ++b2) acc[a][b2] = 0.f;

    for (int k0 = 0; k0 < K; k0 += 32) {
        #pragma unroll
        for (int r = 0; r < BM / 64; ++r) {
            int s = r * 4 + w;      // 16-row segment
            const u16* ga = A + (size_t)(i0 + s * 16 + srow) * lda + (k0 + skoff);
            __builtin_amdgcn_global_load_lds(
                (const __attribute__((address_space(1))) void*)ga,
                (__attribute__((address_space(3))) void*)&As[s * 512], 16, 0, 0);
        }
        #pragma unroll
        for (int r = 0; r < BN / 64; ++r) {
            int s = r * 4 + w;
            const u16* gb = B + (size_t)(j0 + s * 16 + srow) * ldb + (k0 + skoff);
            __builtin_amdgcn_global_load_lds(
                (const __attribute__((address_space(1))) void*)gb,
                (__attribute__((address_space(3))) void*)&Bs[s * 512], 16, 0, 0);
        }
        __syncthreads();

        s16x8 af[MI], bfr[NI];
        #pragma unroll
        for (int mi = 0; mi < MI; ++mi)
            af[mi] = *reinterpret_cast<const s16x8*>(
                &As[(wr * WM + mi * 16 + fr) * 32 + fk]);
        #pragma unroll
        for (int ni = 0; ni < NI; ++ni)
            bfr[ni] = *reinterpret_cast<const s16x8*>(
                &Bs[(wc * WN + ni * 16 + fr) * 32 + fk]);
        #pragma unroll
        for (int mi = 0; mi < MI; ++mi)
            #pragma unroll
            for (int ni = 0; ni < NI; ++ni)
                acc[mi][ni] = __builtin_amdgcn_mfma_f32_16x16x32_bf16(
                    af[mi], bfr[ni], acc[mi][ni], 0, 0, 0);
        __syncthreads();
    }

    const int orow = (l >> 4) * 4;
    const int ocol = l & 15;
    #pragma unroll
    for (int mi = 0; mi < MI; ++mi) {
        #pragma unroll
        for (int ni = 0; ni < NI; ++ni) {
            int ib = i0 + wr * WM + mi * 16 + orow;
            int jb = j0 + wc * WN + ni * 16 + ocol;
            if constexpr (EPI == 0 || EPI == 1 || EPI == 4) {
                u16* D = (u16*)Dp;
                float bj = 0.f;
                if constexpr (EPI == 0) bj = bias[jb];
                #pragma unroll
                for (int e = 0; e < 4; ++e) {
                    float vv = acc[mi][ni][e];
                    if constexpr (EPI == 0) vv += bj;
                    if constexpr (EPI == 1) vv += bias[ib + e];
                    D[(size_t)(ib + e) * Nn + jb] = f2bf(vv);
                }
            } else if constexpr (EPI == 2) {
                float* D = (float*)Dp;
                #pragma unroll
                for (int e = 0; e < 4; ++e)
                    D[(size_t)(ib + e) * Nn + jb] = acc[mi][ni][e] * scl;
            } else {   // EPI == 3
                float* D = (float*)Dp;
                #pragma unroll
                for (int e = 0; e < 4; ++e)
                    D[(size_t)(ib + e) * Nn + jb] =
                        acc[mi][ni][e] + bias[ib + e] + resid[(size_t)(ib + e) * Nn + jb];
            }
        }
    }
}

// q_t/k_t: D[n][co] = sum_ci nx_t[n][ci] * W[co][ci] + b[co].  grid (4,32,8)
__global__ __launch_bounds__(256)
void qk_gemm(const u16* __restrict__ nx_t, const u16* __restrict__ wqb,
             const u16* __restrict__ wkb, const float* __restrict__ bq,
             const float* __restrict__ bk, u16* __restrict__ q_t,
             u16* __restrict__ k_t)
{
    int z = blockIdx.z, b = z & 3, isk = z >> 2;
    gemm_dev<128, 128, 0>(blockIdx.y * 128, blockIdx.x * 128,
                          nx_t + (size_t)b * N_ * C_, isk ? wkb : wqb,
                          (isk ? k_t : q_t) + (size_t)b * N_ * C_,
                          isk ? bk : bq, nullptr, C_, C_, C_, C_, 1.f);
}

// v: D[co][n] = sum_ci Wv[co][ci] * nx_t[n][ci] + bv[co].  grid (32,4,4)
__global__ __launch_bounds__(256)
void v_gemm(const u16* __restrict__ wvb, const u16* __restrict__ nx_t,
            const float* __restrict__ bv, u16* __restrict__ vbuf)
{
    int b = blockIdx.z;
    gemm_dev<128, 128, 1>(blockIdx.y * 128, blockIdx.x * 128,
                          wvb, nx_t + (size_t)b * N_ * C_, vbuf + (size_t)b * C_ * N_,
                          bv, nullptr, N_, C_, C_, C_, 1.f);
}

// scores: S[i][j] = (sum_c q_t[i][c]*k_t[j][c]) / sqrt(C).  grid (32,32,2)
__global__ __launch_bounds__(256)
void scores_gemm(const u16* __restrict__ q_t, const u16* __restrict__ k_t,
                 float* __restrict__ S0, float* __restrict__ S1, int pair)
{
    int z = blockIdx.z, b = pair * 2 + z;
    gemm_dev<128, 128, 2>(blockIdx.y * 128, blockIdx.x * 128,
                          q_t + (size_t)b * N_ * C_, k_t + (size_t)b * N_ * C_,
                          z ? S1 : S0, nullptr, nullptr, N_, C_, C_, C_,
                          0.044194173824159216f);
}

// Row softmax over j; writes P bf16 into the FIRST HALF of each fp32 S row.
// grid (4096, 2)
__global__ __launch_bounds__(256)
void softmax_kernel(float* __restrict__ S0, float* __restrict__ S1)
{
    float* row = (blockIdx.y ? S1 : S0) + (size_t)blockIdx.x * N_;
    int t = threadIdx.x;
    __shared__ float red[256];

    float4 v[4];
    float mx = -1e30f;
    #pragma unroll
    for (int e = 0; e < 4; ++e) {
        v[e] = *reinterpret_cast<const float4*>(row + e * 1024 + t * 4);
        mx = fmaxf(mx, fmaxf(fmaxf(v[e].x, v[e].y), fmaxf(v[e].z, v[e].w)));
    }
    red[t] = mx; __syncthreads();
    for (int off = 128; off > 0; off >>= 1) {
        if (t < off) red[t] = fmaxf(red[t], red[t + off]);
        __syncthreads();
    }
    mx = red[0];
    __syncthreads();

    float sum = 0.f;
    #pragma unroll
    for (int e = 0; e < 4; ++e) {
        v[e].x = __expf(v[e].x - mx); v[e].y = __expf(v[e].y - mx);
        v[e].z = __expf(v[e].z - mx); v[e].w = __expf(v[e].w - mx);
        sum += v[e].x + v[e].y + v[e].z + v[e].w;
    }
    red[t] = sum; __syncthreads();
    for (int off = 128; off > 0; off >>= 1) {
        if (t < off) red[t] += red[t + off];
        __syncthreads();
    }
    float inv = 1.f / red[0];

    u16* P = (u16*)row;     // bf16 row, stride 2*N_ u16 across rows
    #pragma unroll
    for (int e = 0; e < 4; ++e) {
        int j = e * 1024 + t * 4;
        u16x4 o = { f2bf(v[e].x * inv), f2bf(v[e].y * inv),
                    f2bf(v[e].z * inv), f2bf(v[e].w * inv) };
        *reinterpret_cast<u16x4*>(P + j) = o;
    }
}

// PV: attn_t[i][c] = sum_j P[i][j] * v[c][j].  P lda = 2*N_ (in-place rows).
// 1-D grid of 512 with XCD-GATHERING swizzle: the 8 c-tiles consuming the
// same 1 MB P i-tile get block ids congruent mod 8 -> same XCD (round-robin
// dispatch) -> P tile is fetched into that XCD's L2 once instead of 8 HBM
// re-reads. Bijection: id=(slot<<3)|xcd; yz=xcd*8+(slot>>3); ct=slot&7.
__global__ __launch_bounds__(256)
void pv_gemm(const float* __restrict__ S0, const float* __restrict__ S1,
             const u16* __restrict__ vbuf, u16* __restrict__ attn_t, int pair)
{
    int id  = blockIdx.x;          // 0..511
    int xcd = id & 7, slot = id >> 3;
    int yz  = xcd * 8 + (slot >> 3);   // 0..63: which (i-tile, z)
    int ct  = slot & 7;                // c-tile 0..7
    int iy  = yz & 31, z = yz >> 5;
    int b = pair * 2 + z;
    const u16* P = (const u16*)(z ? S1 : S0);
    gemm_dev<128, 64, 4>(iy * 128, ct * 64,
                         P, vbuf + (size_t)b * C_ * N_, attn_t + (size_t)b * N_ * C_,
                         nullptr, nullptr, C_, N_, 2 * N_, N_, 1.f);
}

// final: out[co][n] = x + bo[co] + sum_ci wo[co][ci]*attn_t[n][ci]. grid (32,4,4)
__global__ __launch_bounds__(256)
void final_gemm(const u16* __restrict__ wob, const u16* __restrict__ attn_t,
                const float* __restrict__ bo, const float* __restrict__ x,
                float* __restrict__ outp)
{
    int b = blockIdx.z;
    gemm_dev<128, 128, 3>(blockIdx.y * 128, blockIdx.x * 128,
                          wob, attn_t + (size_t)b * N_ * C_, outp + (size_t)b * C_ * N_,
                          bo, x + (size_t)b * C_ * N_, N_, C_, C_, C_, 1.f);
}

// ---------------------------------------------------------------------------
extern "C" void kernel_launch(void* const* d_in, const int* in_sizes, int n_in,
                              void* d_out, int out_size, void* d_ws, size_t ws_size,
                              hipStream_t stream)
{
    const float* x     = (const float*)d_in[0];
    const float* gamma = (const float*)d_in[1];
    const float* beta  = (const float*)d_in[2];
    const float* wq    = (const float*)d_in[3];
    const float* bq    = (const float*)d_in[4];
    const float* wk    = (const float*)d_in[5];
    const float* bk    = (const float*)d_in[6];
    const float* wv    = (const float*)d_in[7];
    const float* bv    = (const float*)d_in[8];
    const float* wo    = (const float*)d_in[9];
    const float* bo    = (const float*)d_in[10];
    float* out = (float*)d_out;

    // Workspace carve (total ~194 MB):
    char* p = (char*)d_ws;
    auto take = [&](size_t bytes) { char* r = p; p += (bytes + 255) & ~(size_t)255; return r; };
    float* scale = (float*)take(B_ * C_ * 4);
    float* shift = (float*)take(B_ * C_ * 4);
    u16* wqb = (u16*)take((size_t)C_ * C_ * 2);
    u16* wkb = (u16*)take((size_t)C_ * C_ * 2);
    u16* wvb = (u16*)take((size_t)C_ * C_ * 2);
    u16* wob = (u16*)take((size_t)C_ * C_ * 2);
    u16* nx_t  = (u16*)take((size_t)B_ * N_ * C_ * 2);   // reused as attn_t
    u16* q_t   = (u16*)take((size_t)B_ * N_ * C_ * 2);
    u16* k_t   = (u16*)take((size_t)B_ * N_ * C_ * 2);
    u16* vbuf  = (u16*)take((size_t)B_ * C_ * N_ * 2);
    float* S0  = (float*)take((size_t)N_ * N_ * 4);
    float* S1  = (float*)take((size_t)N_ * N_ * 4);
    u16* attn_t = nx_t;    // nx_t is dead after qkv projections

    gn_stats_kernel<<<128, 256, 0, stream>>>(x, gamma, beta, scale, shift);
    wcvt_kernel<<<256, 256, 0, stream>>>(wq, wk, wv, wo, wqb, wkb, wvb, wob);
    nxt_kernel<<<dim3(N_ / 64, C_ / 64, B_), 256, 0, stream>>>(x, scale, shift, nx_t);

    qk_gemm<<<dim3(C_ / 128, N_ / 128, 8), 256, 0, stream>>>(nx_t, wqb, wkb, bq, bk, q_t, k_t);
    v_gemm<<<dim3(N_ / 128, C_ / 128, B_), 256, 0, stream>>>(wvb, nx_t, bv, vbuf);

    for (int pair = 0; pair < 2; ++pair) {
        scores_gemm<<<dim3(N_ / 128, N_ / 128, 2), 256, 0, stream>>>(q_t, k_t, S0, S1, pair);
        softmax_kernel<<<dim3(N_, 2), 256, 0, stream>>>(S0, S1);
        pv_gemm<<<512, 256, 0, stream>>>(S0, S1, vbuf, attn_t, pair);
    }

    final_gemm<<<dim3(N_ / 128, C_ / 128, B_), 256, 0, stream>>>(wob, attn_t, bo, x, out);
}

// Round 5
// 358.465 us; speedup vs baseline: 1.4795x; 1.1558x over previous
//
#include <hip/hip_runtime.h>

// Problem constants (B=4, C=512, G=32, H=W=64)
#define B_   4
#define C_   512
#define G_   32
#define CPG  16          // channels per group
#define N_   4096        // H*W

typedef unsigned short u16;
typedef __attribute__((ext_vector_type(4))) float f32x4;
typedef __attribute__((ext_vector_type(8))) short s16x8;
typedef __attribute__((ext_vector_type(8))) u16   u16x8;
typedef __attribute__((ext_vector_type(4))) u16   u16x4;

__device__ __forceinline__ u16 f2bf(float f) {
    union { float f; unsigned u; } x; x.f = f;
    unsigned r = x.u + 0x7fffu + ((x.u >> 16) & 1u);   // RNE
    return (u16)(r >> 16);
}

// ---------------------------------------------------------------------------
// GroupNorm statistics: one block per (b, g). Writes per-channel scale/shift.
// ---------------------------------------------------------------------------
__global__ __launch_bounds__(256)
void gn_stats_kernel(const float* __restrict__ x,
                     const float* __restrict__ gamma,
                     const float* __restrict__ beta,
                     float* __restrict__ scale,   // [B*C]
                     float* __restrict__ shift)   // [B*C]
{
    int bg = blockIdx.x;            // 0..127
    int b = bg >> 5, g = bg & 31;
    const float* base = x + (size_t)(b * C_ + g * CPG) * N_;
    const int nelem = CPG * N_;     // 65536
    int t = threadIdx.x;

    float s = 0.f, ss = 0.f;
    for (int i = t * 4; i < nelem; i += 256 * 4) {
        float4 v = *reinterpret_cast<const float4*>(base + i);
        s  += v.x + v.y + v.z + v.w;
        ss += v.x * v.x + v.y * v.y + v.z * v.z + v.w * v.w;
    }
    __shared__ float rs[256], rss[256];
    rs[t] = s; rss[t] = ss;
    __syncthreads();
    for (int off = 128; off > 0; off >>= 1) {
        if (t < off) { rs[t] += rs[t + off]; rss[t] += rss[t + off]; }
        __syncthreads();
    }
    __shared__ float mean_s, rstd_s;
    if (t == 0) {
        float mean = rs[0] / (float)nelem;
        float var  = rss[0] / (float)nelem - mean * mean;
        mean_s = mean;
        rstd_s = rsqrtf(var + 1e-6f);
    }
    __syncthreads();
    if (t < CPG) {
        int c = g * CPG + t;
        float sc = gamma[c] * rstd_s;
        scale[b * C_ + c] = sc;
        shift[b * C_ + c] = beta[c] - mean_s * sc;
    }
}

// ---------------------------------------------------------------------------
// Convert the four 512x512 weight matrices to bf16 (same [co][ci] layout).
// ---------------------------------------------------------------------------
__global__ __launch_bounds__(256)
void wcvt_kernel(const float* __restrict__ wq, const float* __restrict__ wk,
                 const float* __restrict__ wv, const float* __restrict__ wo,
                 u16* __restrict__ wqb, u16* __restrict__ wkb,
                 u16* __restrict__ wvb, u16* __restrict__ wob)
{
    int idx = (blockIdx.x * 256 + threadIdx.x) * 4;
    {
        float4 a = *reinterpret_cast<const float4*>(wq + idx);
        u16x4 r = { f2bf(a.x), f2bf(a.y), f2bf(a.z), f2bf(a.w) };
        *reinterpret_cast<u16x4*>(wqb + idx) = r;
    }
    {
        float4 a = *reinterpret_cast<const float4*>(wk + idx);
        u16x4 r = { f2bf(a.x), f2bf(a.y), f2bf(a.z), f2bf(a.w) };
        *reinterpret_cast<u16x4*>(wkb + idx) = r;
    }
    {
        float4 a = *reinterpret_cast<const float4*>(wv + idx);
        u16x4 r = { f2bf(a.x), f2bf(a.y), f2bf(a.z), f2bf(a.w) };
        *reinterpret_cast<u16x4*>(wvb + idx) = r;
    }
    {
        float4 a = *reinterpret_cast<const float4*>(wo + idx);
        u16x4 r = { f2bf(a.x), f2bf(a.y), f2bf(a.z), f2bf(a.w) };
        *reinterpret_cast<u16x4*>(wob + idx) = r;
    }
}

// ---------------------------------------------------------------------------
// GN-apply + transpose + bf16 convert: x[b][c][n] f32 -> nx_t[b][n][c] bf16.
// ---------------------------------------------------------------------------
__global__ __launch_bounds__(256)
void nxt_kernel(const float* __restrict__ x, const float* __restrict__ scale,
                const float* __restrict__ shift, u16* __restrict__ nx_t)
{
    int b  = blockIdx.z;
    int n0 = blockIdx.x * 64, c0 = blockIdx.y * 64;
    const float* xb = x + ((size_t)b * C_ + c0) * N_ + n0;
    u16* ob = nx_t + ((size_t)b * N_ + n0) * C_ + c0;
    int t = threadIdx.x;
    int tx = t & 15, ty = t >> 4;

    __shared__ float tile[64][65];
    #pragma unroll
    for (int r = 0; r < 4; ++r) {
        int c = ty * 4 + r;
        float sc = scale[b * C_ + c0 + c];
        float sh = shift[b * C_ + c0 + c];
        float4 v = *reinterpret_cast<const float4*>(xb + (size_t)c * N_ + tx * 4);
        tile[c][tx * 4 + 0] = v.x * sc + sh;
        tile[c][tx * 4 + 1] = v.y * sc + sh;
        tile[c][tx * 4 + 2] = v.z * sc + sh;
        tile[c][tx * 4 + 3] = v.w * sc + sh;
    }
    __syncthreads();
    int nn = t >> 2, cc0 = (t & 3) * 16;
    u16x8 o0, o1;
    #pragma unroll
    for (int j = 0; j < 8; ++j) o0[j] = f2bf(tile[cc0 + j][nn]);
    #pragma unroll
    for (int j = 0; j < 8; ++j) o1[j] = f2bf(tile[cc0 + 8 + j][nn]);
    *reinterpret_cast<u16x8*>(ob + (size_t)nn * C_ + cc0)     = o0;
    *reinterpret_cast<u16x8*>(ob + (size_t)nn * C_ + cc0 + 8) = o1;
}

// ---------------------------------------------------------------------------
// TN bf16 MFMA GEMM: D[i][j] = sum_k A[i][k] * B[j][k]
// BM x BN tile, BK=64, 4 waves (2x2), 16x16x32 MFMA, global_load_lds staging.
// LDS row = 64 u16 = 128 B. Granule XOR-swizzle (both-sides): stored 16B
// granule position p of row r holds logical granule p ^ (r&7); achieved by
// pre-swizzling the GLOBAL source k-offset (gload_lds dest stays linear) and
// applying the same XOR on the ds_read address. Keeps b128 reads at the
// 8-clock structural floor instead of a 16-way conflict.
// EPI: 0 = bf16 out + bias[j]; 1 = bf16 out + bias[i]; 2 = f32 out * scale;
//      3 = f32 out + bias[i] + resid[i][j]; 4 = bf16 out plain.
// ---------------------------------------------------------------------------
template<int BM, int BN, int EPI>
__device__ __forceinline__
void gemm_dev(int i0, int j0,
              const u16* __restrict__ A, const u16* __restrict__ B,
              void* __restrict__ Dp, const float* __restrict__ bias,
              const float* __restrict__ resid,
              int Nn, int K, int lda, int ldb, float scl)
{
    constexpr int WM = BM / 2, WN = BN / 2;   // wave tile
    constexpr int MI = WM / 16, NI = WN / 16; // fragments per wave

    __shared__ u16 As[BM * 64];
    __shared__ u16 Bs[BN * 64];

    const int t  = threadIdx.x;
    const int l  = t & 63;
    const int w  = t >> 6;          // wave 0..3
    const int wr = w >> 1;          // i-half
    const int wc = w & 1;           // j-half

    const int srow = l >> 3;                    // row within 8-row segment
    const int sgr  = ((l & 7) ^ (l >> 3)) * 8;  // swizzled global k-offset (u16)

    const int fr = l & 15;          // fragment row
    const int q  = l >> 4;          // fragment k-quarter (granule within 32-k)

    f32x4 acc[MI][NI];
    #pragma unroll
    for (int a = 0; a < MI; ++a)
        #pragma unroll
        for (int b2 = 0; b2 < NI; ++b2) acc[a][b2] = 0.f;

    for (int k0 = 0; k0 < K; k0 += 64) {
        #pragma unroll
        for (int r = 0; r < BM / 32; ++r) {
            int s = r * 4 + w;      // 8-row segment
            const u16* ga = A + (size_t)(i0 + s * 8 + srow) * lda + (k0 + sgr);
            __builtin_amdgcn_global_load_lds(
                (const __attribute__((address_space(1))) void*)ga,
                (__attribute__((address_space(3))) void*)&As[s * 512], 16, 0, 0);
        }
        #pragma unroll
        for (int r = 0; r < BN / 32; ++r) {
            int s = r * 4 + w;
            const u16* gb = B + (size_t)(j0 + s * 8 + srow) * ldb + (k0 + sgr);
            __builtin_amdgcn_global_load_lds(
                (const __attribute__((address_space(1))) void*)gb,
                (__attribute__((address_space(3))) void*)&Bs[s * 512], 16, 0, 0);
        }
        __syncthreads();

        #pragma unroll
        for (int h = 0; h < 2; ++h) {
            s16x8 af[MI], bfr[NI];
            #pragma unroll
            for (int mi = 0; mi < MI; ++mi) {
                int r = wr * WM + mi * 16 + fr;
                int p = (h * 4 + q) ^ (r & 7);
                af[mi] = *reinterpret_cast<const s16x8*>(&As[r * 64 + p * 8]);
            }
            #pragma unroll
            for (int ni = 0; ni < NI; ++ni) {
                int r = wc * WN + ni * 16 + fr;
                int p = (h * 4 + q) ^ (r & 7);
                bfr[ni] = *reinterpret_cast<const s16x8*>(&Bs[r * 64 + p * 8]);
            }
            #pragma unroll
            for (int mi = 0; mi < MI; ++mi)
                #pragma unroll
                for (int ni = 0; ni < NI; ++ni)
                    acc[mi][ni] = __builtin_amdgcn_mfma_f32_16x16x32_bf16(
                        af[mi], bfr[ni], acc[mi][ni], 0, 0, 0);
        }
        __syncthreads();
    }

    const int orow = (l >> 4) * 4;
    const int ocol = l & 15;
    #pragma unroll
    for (int mi = 0; mi < MI; ++mi) {
        #pragma unroll
        for (int ni = 0; ni < NI; ++ni) {
            int ib = i0 + wr * WM + mi * 16 + orow;
            int jb = j0 + wc * WN + ni * 16 + ocol;
            if constexpr (EPI == 0 || EPI == 1 || EPI == 4) {
                u16* D = (u16*)Dp;
                float bj = 0.f;
                if constexpr (EPI == 0) bj = bias[jb];
                #pragma unroll
                for (int e = 0; e < 4; ++e) {
                    float vv = acc[mi][ni][e];
                    if constexpr (EPI == 0) vv += bj;
                    if constexpr (EPI == 1) vv += bias[ib + e];
                    D[(size_t)(ib + e) * Nn + jb] = f2bf(vv);
                }
            } else if constexpr (EPI == 2) {
                float* D = (float*)Dp;
                #pragma unroll
                for (int e = 0; e < 4; ++e)
                    D[(size_t)(ib + e) * Nn + jb] = acc[mi][ni][e] * scl;
            } else {   // EPI == 3
                float* D = (float*)Dp;
                #pragma unroll
                for (int e = 0; e < 4; ++e)
                    D[(size_t)(ib + e) * Nn + jb] =
                        acc[mi][ni][e] + bias[ib + e] + resid[(size_t)(ib + e) * Nn + jb];
            }
        }
    }
}

// q_t/k_t: D[n][co] = sum_ci nx_t[n][ci] * W[co][ci] + b[co].  grid (4,32,8)
__global__ __launch_bounds__(256)
void qk_gemm(const u16* __restrict__ nx_t, const u16* __restrict__ wqb,
             const u16* __restrict__ wkb, const float* __restrict__ bq,
             const float* __restrict__ bk, u16* __restrict__ q_t,
             u16* __restrict__ k_t)
{
    int z = blockIdx.z, b = z & 3, isk = z >> 2;
    gemm_dev<128, 128, 0>(blockIdx.y * 128, blockIdx.x * 128,
                          nx_t + (size_t)b * N_ * C_, isk ? wkb : wqb,
                          (isk ? k_t : q_t) + (size_t)b * N_ * C_,
                          isk ? bk : bq, nullptr, C_, C_, C_, C_, 1.f);
}

// v: D[co][n] = sum_ci Wv[co][ci] * nx_t[n][ci] + bv[co].  grid (32,4,4)
__global__ __launch_bounds__(256)
void v_gemm(const u16* __restrict__ wvb, const u16* __restrict__ nx_t,
            const float* __restrict__ bv, u16* __restrict__ vbuf)
{
    int b = blockIdx.z;
    gemm_dev<128, 128, 1>(blockIdx.y * 128, blockIdx.x * 128,
                          wvb, nx_t + (size_t)b * N_ * C_, vbuf + (size_t)b * C_ * N_,
                          bv, nullptr, N_, C_, C_, C_, 1.f);
}

// scores: S[z][i][j] = (sum_c q_t[i][c]*k_t[j][c]) / sqrt(C).  grid (32,32,nb)
__global__ __launch_bounds__(256)
void scores_gemm(const u16* __restrict__ q_t, const u16* __restrict__ k_t,
                 float* __restrict__ S, int b0)
{
    int z = blockIdx.z, b = b0 + z;
    gemm_dev<128, 128, 2>(blockIdx.y * 128, blockIdx.x * 128,
                          q_t + (size_t)b * N_ * C_, k_t + (size_t)b * N_ * C_,
                          S + (size_t)z * N_ * N_, nullptr, nullptr, N_, C_, C_, C_,
                          0.044194173824159216f);
}

// Row softmax over j; writes P bf16 into the FIRST HALF of each fp32 S row.
// grid (4096, nb)
__global__ __launch_bounds__(256)
void softmax_kernel(float* __restrict__ S)
{
    float* row = S + (size_t)blockIdx.y * N_ * N_ + (size_t)blockIdx.x * N_;
    int t = threadIdx.x;
    __shared__ float red[256];

    float4 v[4];
    float mx = -1e30f;
    #pragma unroll
    for (int e = 0; e < 4; ++e) {
        v[e] = *reinterpret_cast<const float4*>(row + e * 1024 + t * 4);
        mx = fmaxf(mx, fmaxf(fmaxf(v[e].x, v[e].y), fmaxf(v[e].z, v[e].w)));
    }
    red[t] = mx; __syncthreads();
    for (int off = 128; off > 0; off >>= 1) {
        if (t < off) red[t] = fmaxf(red[t], red[t + off]);
        __syncthreads();
    }
    mx = red[0];
    __syncthreads();

    float sum = 0.f;
    #pragma unroll
    for (int e = 0; e < 4; ++e) {
        v[e].x = __expf(v[e].x - mx); v[e].y = __expf(v[e].y - mx);
        v[e].z = __expf(v[e].z - mx); v[e].w = __expf(v[e].w - mx);
        sum += v[e].x + v[e].y + v[e].z + v[e].w;
    }
    red[t] = sum; __syncthreads();
    for (int off = 128; off > 0; off >>= 1) {
        if (t < off) red[t] += red[t + off];
        __syncthreads();
    }
    float inv = 1.f / red[0];

    u16* P = (u16*)row;     // bf16 row, stride 2*N_ u16 across rows
    #pragma unroll
    for (int e = 0; e < 4; ++e) {
        int j = e * 1024 + t * 4;
        u16x4 o = { f2bf(v[e].x * inv), f2bf(v[e].y * inv),
                    f2bf(v[e].z * inv), f2bf(v[e].w * inv) };
        *reinterpret_cast<u16x4*>(P + j) = o;
    }
}

// PV: attn_t[i][c] = sum_j P[i][j] * v[c][j].  P lda = 2*N_ (in-place rows).
// 1-D grid of nb*256 with XCD-GATHERING swizzle: the 8 c-tiles consuming the
// same P i-tile get block ids congruent mod 8 -> same XCD -> P fetched into
// that XCD's L2 once. id=(slot<<3)|xcd; yz=xcd*4*nb+(slot>>3); ct=slot&7.
__global__ __launch_bounds__(256)
void pv_gemm(const float* __restrict__ S, const u16* __restrict__ vbuf,
             u16* __restrict__ attn_t, int b0, int nb)
{
    int id  = blockIdx.x;
    int xcd = id & 7, slot = id >> 3;
    int yz  = xcd * 4 * nb + (slot >> 3);   // (i-tile, z) combo
    int ct  = slot & 7;                     // c-tile 0..7
    int iy  = yz & 31, z = yz >> 5;
    int b = b0 + z;
    const u16* P = (const u16*)(S + (size_t)z * N_ * N_);
    gemm_dev<128, 64, 4>(iy * 128, ct * 64,
                         P, vbuf + (size_t)b * C_ * N_, attn_t + (size_t)b * N_ * C_,
                         nullptr, nullptr, C_, N_, 2 * N_, N_, 1.f);
}

// final: out[co][n] = x + bo[co] + sum_ci wo[co][ci]*attn_t[n][ci]. grid (32,4,4)
__global__ __launch_bounds__(256)
void final_gemm(const u16* __restrict__ wob, const u16* __restrict__ attn_t,
                const float* __restrict__ bo, const float* __restrict__ x,
                float* __restrict__ outp)
{
    int b = blockIdx.z;
    gemm_dev<128, 128, 3>(blockIdx.y * 128, blockIdx.x * 128,
                          wob, attn_t + (size_t)b * N_ * C_, outp + (size_t)b * C_ * N_,
                          bo, x + (size_t)b * C_ * N_, N_, C_, C_, C_, 1.f);
}

// ---------------------------------------------------------------------------
extern "C" void kernel_launch(void* const* d_in, const int* in_sizes, int n_in,
                              void* d_out, int out_size, void* d_ws, size_t ws_size,
                              hipStream_t stream)
{
    const float* x     = (const float*)d_in[0];
    const float* gamma = (const float*)d_in[1];
    const float* beta  = (const float*)d_in[2];
    const float* wq    = (const float*)d_in[3];
    const float* bq    = (const float*)d_in[4];
    const float* wk    = (const float*)d_in[5];
    const float* bk    = (const float*)d_in[6];
    const float* wv    = (const float*)d_in[7];
    const float* bv    = (const float*)d_in[8];
    const float* wo    = (const float*)d_in[9];
    const float* bo    = (const float*)d_in[10];
    float* out = (float*)d_out;

    // Workspace carve. Base ~70 MB + S buffers (67 MB each).
    char* p = (char*)d_ws;
    auto take = [&](size_t bytes) { char* r = p; p += (bytes + 255) & ~(size_t)255; return r; };
    float* scale = (float*)take(B_ * C_ * 4);
    float* shift = (float*)take(B_ * C_ * 4);
    u16* wqb = (u16*)take((size_t)C_ * C_ * 2);
    u16* wkb = (u16*)take((size_t)C_ * C_ * 2);
    u16* wvb = (u16*)take((size_t)C_ * C_ * 2);
    u16* wob = (u16*)take((size_t)C_ * C_ * 2);
    u16* nx_t  = (u16*)take((size_t)B_ * N_ * C_ * 2);   // reused as attn_t
    u16* q_t   = (u16*)take((size_t)B_ * N_ * C_ * 2);
    u16* k_t   = (u16*)take((size_t)B_ * N_ * C_ * 2);
    u16* vbuf  = (u16*)take((size_t)B_ * C_ * N_ * 2);
    size_t base_used = (size_t)(p - (char*)d_ws);
    size_t s_bytes = (size_t)N_ * N_ * 4;
    // 4-batch path if workspace holds 4 S buffers, else pair path (2).
    bool four = ws_size >= base_used + 4 * s_bytes + 1024;
    float* S = (float*)take(s_bytes * (four ? 4 : 2));
    u16* attn_t = nx_t;    // nx_t is dead after qkv projections

    gn_stats_kernel<<<128, 256, 0, stream>>>(x, gamma, beta, scale, shift);
    wcvt_kernel<<<256, 256, 0, stream>>>(wq, wk, wv, wo, wqb, wkb, wvb, wob);
    nxt_kernel<<<dim3(N_ / 64, C_ / 64, B_), 256, 0, stream>>>(x, scale, shift, nx_t);

    qk_gemm<<<dim3(C_ / 128, N_ / 128, 8), 256, 0, stream>>>(nx_t, wqb, wkb, bq, bk, q_t, k_t);
    v_gemm<<<dim3(N_ / 128, C_ / 128, B_), 256, 0, stream>>>(wvb, nx_t, bv, vbuf);

    if (four) {
        scores_gemm<<<dim3(N_ / 128, N_ / 128, 4), 256, 0, stream>>>(q_t, k_t, S, 0);
        softmax_kernel<<<dim3(N_, 4), 256, 0, stream>>>(S);
        pv_gemm<<<4 * 256, 256, 0, stream>>>(S, vbuf, attn_t, 0, 4);
    } else {
        for (int pair = 0; pair < 2; ++pair) {
            scores_gemm<<<dim3(N_ / 128, N_ / 128, 2), 256, 0, stream>>>(q_t, k_t, S, pair * 2);
            softmax_kernel<<<dim3(N_, 2), 256, 0, stream>>>(S);
            pv_gemm<<<2 * 256, 256, 0, stream>>>(S, vbuf, attn_t, pair * 2, 2);
        }
    }

    final_gemm<<<dim3(N_ / 128, C_ / 128, B_), 256, 0, stream>>>(wob, attn_t, bo, x, out);
}